// Round 5
// baseline (16258.438 us; speedup 1.0000x reference)
//
#include <hip/hip_runtime.h>
#include <cstdint>
#include <cstddef>

// Problem dims: B=32, T=2048, D=512, H=512, 4H=2048
#define TT 2048
#define DD 512

// ---------------------------------------------------------------------------
// Phase 1 (chunked): xp = inputs @ Wi + b, layout: xp[tl][gate 4][B 32][col 512]
// fp32 vector GEMM, 128x128x16 tiles, 8x8 per thread.  (unchanged)
// ---------------------------------------------------------------------------
#define BM 128
#define BN 128
#define BK 16

__global__ __launch_bounds__(256) void xproj_gemm(
    const float* __restrict__ A,    // [32*2048, 512]
    const float* __restrict__ W,    // [512, 2048]
    const float* __restrict__ bias, // [2048]
    float* __restrict__ C,          // xp chunk
    int t0, int tmask, int tlog)    // T_CH = tmask+1 = 1<<tlog
{
    __shared__ __align__(16) float As[BK][BM + 4];   // [k][m], transposed on load
    __shared__ __align__(16) float Bs[BK][BN + 4];   // [k][n]
    const int tid = threadIdx.x;
    const int nt = blockIdx.x;
    const int mt = blockIdx.y;
    const int m_base = mt * BM;        // chunk-local row (m = bglob*T_CH + tl)
    const int n_base = nt * BN;
    const int ty = tid >> 4;
    const int tx = tid & 15;

    float acc[8][8];
#pragma unroll
    for (int i = 0; i < 8; ++i)
#pragma unroll
        for (int j = 0; j < 8; ++j) acc[i][j] = 0.f;

    for (int k0 = 0; k0 < DD; k0 += BK) {
#pragma unroll
        for (int j = 0; j < 2; ++j) {
            int idx = tid * 2 + j;             // 0..511
            int rowl = idx >> 2, q = idx & 3;  // A: 128 rows x 4 float4
            int rc = m_base + rowl;            // chunk-local row
            int rg = ((rc >> tlog) << 11) + t0 + (rc & tmask);  // global input row
            float4 av = *(const float4*)(A + (size_t)rg * DD + k0 + q * 4);
            As[q * 4 + 0][rowl] = av.x;
            As[q * 4 + 1][rowl] = av.y;
            As[q * 4 + 2][rowl] = av.z;
            As[q * 4 + 3][rowl] = av.w;
            int kr = idx >> 5, nq = idx & 31;  // B: 16 rows x 32 float4
            *(float4*)&Bs[kr][nq * 4] =
                *(const float4*)(W + (size_t)(k0 + kr) * 2048 + n_base + nq * 4);
        }
        __syncthreads();
#pragma unroll
        for (int kk = 0; kk < BK; ++kk) {
            float a[8], bb[8];
            *(float4*)&a[0]  = *(const float4*)&As[kk][ty * 8];
            *(float4*)&a[4]  = *(const float4*)&As[kk][ty * 8 + 4];
            *(float4*)&bb[0] = *(const float4*)&Bs[kk][tx * 8];
            *(float4*)&bb[4] = *(const float4*)&Bs[kk][tx * 8 + 4];
#pragma unroll
            for (int i = 0; i < 8; ++i)
#pragma unroll
                for (int j = 0; j < 8; ++j)
                    acc[i][j] = fmaf(a[i], bb[j], acc[i][j]);
        }
        __syncthreads();
    }
#pragma unroll
    for (int i = 0; i < 8; ++i) {
        int m = m_base + ty * 8 + i;
        int bglob = m >> tlog, tl = m & tmask;
#pragma unroll
        for (int j = 0; j < 8; j += 4) {
            int n = n_base + tx * 8 + j;
            int gate = n >> 9, c = n & 511;    // 8-aligned run never crosses gate
            float4 v;
            v.x = acc[i][j + 0] + bias[n + 0];
            v.y = acc[i][j + 1] + bias[n + 1];
            v.z = acc[i][j + 2] + bias[n + 2];
            v.w = acc[i][j + 3] + bias[n + 3];
            size_t addr = (((size_t)tl * 4 + gate) * 32 + bglob) * 512 + c;
            *(float4*)(C + addr) = v;
        }
    }
}

// ---------------------------------------------------------------------------
// Phase 2: persistent LSTM scan. Data-poll sync (no flags/barriers): h rotates
// through 3 buffers; slots poisoned (0xFFFFFFFF NaN, unreachable by
// h = o*tanh(c) in (-1,1)) by their owner one step after consumption, drained
// by the vmcnt(0) before the next h-store (drain-then-signal, data = signal).
//
// NEW geometry (R4's VGPR=100 proved the 128-float Wh fragment was NOT
// register-resident -> per-step L2 re-reads ~64 MB/step grid-wide):
//   8 groups x 32 blocks x 512 threads (1 block/CU). Group g owns batches
//   [4g, 4g+4). Block p owns h-cols [16p, 16p+16). Wave w owns 2 cols
//   (16p+2w), all 4 gates, all 4 batches. Lane l owns k in {2l,2l+1} per
//   128-quarter -> weight fragment = 64 floats (32 float2), PINNED into
//   VGPRs via empty asm (blocks invariant-load rematerialization).
// Dot = 256 FMA/lane/step (same as before); identical accumulation order
// and butterfly -> bit-identical numerics.
// ---------------------------------------------------------------------------
#define NGRP 8
#define BPG  32
#define HSZ  (32 * 512)          // one h buffer (floats)
#define POISON 0xFFFFFFFFu

__device__ __forceinline__ float2 ldg_agent_f2(const float* p) {
    double d = __hip_atomic_load((const double*)p, __ATOMIC_RELAXED,
                                 __HIP_MEMORY_SCOPE_AGENT);
    return __builtin_bit_cast(float2, d);
}

// butterfly reduce step: halve the live value count across lanes differing in bit D
template<int D, int HALF>
__device__ __forceinline__ void rstep(float* p, int lane) {
    const bool hi = (lane & D) != 0;
#pragma unroll
    for (int i = 0; i < HALF; ++i) {
        float send = hi ? p[i] : p[i + HALF];
        float recv = __shfl_xor(send, D, 64);
        p[i] = (hi ? p[i + HALF] : p[i]) + recv;
    }
}

__global__ __launch_bounds__(512, 2) void lstm_scan(
    const float* __restrict__ xp,   // [tl][gate 4][B 32][col 512]
    const float* __restrict__ Wh,   // [512, 2048]
    const float* __restrict__ c0,   // [32, 512]
    const float* __restrict__ h0,   // [32, 512]
    float* __restrict__ out,        // [32, 2048, 512]
    float* hbuf,                    // [3][32][512] rotating (persists)
    float* __restrict__ cbuf,       // [32][512] c-state (persists)
    int t0, int T_CH)
{
    const int tid  = threadIdx.x;
    const int blk  = blockIdx.x;
    const int g    = blk >> 5;      // group 0..7 (4 batches each)
    const int p    = blk & 31;      // block-in-group (16 cols each)
    const int lane = tid & 63;
    const int w    = tid >> 6;      // wave 0..7
    const int colb = p * 16 + 2 * w;   // wave's 2 owned h-cols

    // active gate lanes: l%4==0, l<32. idx = bitrev5(l) = gate*8 + cc*4 + b.
    const bool act = ((lane & 3) == 0) && (lane < 32);
    const int r_ = lane >> 2;
    const int cc = r_ & 1;
    const int bb = (((r_ >> 1) & 1) << 1) | ((r_ >> 2) & 1);
    const int B  = 4 * g + bb;
    const int col = colb + cc;

    float creg = 0.f;
    float xr[4] = {0.f, 0.f, 0.f, 0.f}, xn[4] = {0.f, 0.f, 0.f, 0.f};
    if (act) {
        size_t o = (size_t)B * 512 + col;
        if (t0 == 0) {
            creg = c0[o];
            float hv = h0[o];
            if (__float_as_uint(hv) == POISON) hv = __uint_as_float(0xFFFFFFFEu);
            // fill buf[0] early; consumers poll this very data (no drain needed)
            __hip_atomic_store(hbuf + o, hv, __ATOMIC_RELAXED, __HIP_MEMORY_SCOPE_AGENT);
        } else {
            creg = cbuf[o];   // h_{t0} already in hbuf[t0%3] from prev chunk
        }
#pragma unroll
        for (int gate = 0; gate < 4; ++gate)     // xp prefetch for tl=0
            xr[gate] = xp[((size_t)0 * 4 + gate) * HSZ + (size_t)B * 512 + col];
    }

    // ---- Wh fragment -> registers (once): 32 float2, 64 VGPRs.
    // wv[gate*8+q*2+s] = Wh[128q + 2*lane + s][gate*512 + colb + (0..1)]
    float2 wv[32];
#pragma unroll
    for (int gate = 0; gate < 4; ++gate)
#pragma unroll
        for (int q = 0; q < 4; ++q)
#pragma unroll
            for (int s = 0; s < 2; ++s)
                wv[gate * 8 + q * 2 + s] =
                    *(const float2*)(Wh + (size_t)(128 * q + 2 * lane + s) * 2048
                                     + gate * 512 + colb);
    // PIN: force materialization into VGPRs; the asm def is not
    // rematerializable, so the invariant loads cannot be sunk into the loop
    // (R4's VGPR=100 + FETCH +87MB showed exactly that sinking).
#pragma unroll
    for (int i = 0; i < 32; ++i)
        asm volatile("" : "+v"(wv[i].x), "+v"(wv[i].y));

    for (int tl = 0; tl < T_CH; ++tl) {
        const int t = t0 + tl;
        const int cur  = t % 3;            // read h_t here
        const int nxt  = (t + 1) % 3;      // write h_{t+1} here
        const int rcy  = (t + 2) % 3;      // recycle: poison own slots here

        // ---- poll h_t directly: 16 coalesced 8B loads, retry on poison ----
        const float* hp = hbuf + (size_t)cur * HSZ + (size_t)(4 * g) * 512 + 2 * lane;
        float2 hd[4][4];
        for (;;) {
            bool ok = true;
#pragma unroll
            for (int b = 0; b < 4; ++b)
#pragma unroll
                for (int q = 0; q < 4; ++q) {
                    hd[b][q] = ldg_agent_f2(hp + b * 512 + q * 128);
                    uint2 u = __builtin_bit_cast(uint2, hd[b][q]);
                    ok = ok & (u.x != POISON) & (u.y != POISON);
                }
            if (ok) break;
            __builtin_amdgcn_s_sleep(1);
        }

        // ---- poison own slots of the recycle buffer (issued early; the
        // vmcnt(0) before the h-store orders poison -> h_{t+1} visibility) ----
        if (act)
            __hip_atomic_store(hbuf + (size_t)rcy * HSZ + (size_t)B * 512 + col,
                               __uint_as_float(POISON),
                               __ATOMIC_RELAXED, __HIP_MEMORY_SCOPE_AGENT);

        // ---- dot: pp[gate*8 + cc*4 + b], k = 128q + 2l + s ----
        float pp[32];
#pragma unroll
        for (int i = 0; i < 32; ++i) pp[i] = 0.f;
#pragma unroll
        for (int b = 0; b < 4; ++b)
#pragma unroll
            for (int q = 0; q < 4; ++q) {
                const float2 h2 = hd[b][q];
#pragma unroll
                for (int s = 0; s < 2; ++s) {
                    const float hs = s ? h2.y : h2.x;
#pragma unroll
                    for (int gate = 0; gate < 4; ++gate) {
                        const float2 wq = wv[gate * 8 + q * 2 + s];
                        pp[gate * 8 + 0 + b] = fmaf(hs, wq.x, pp[gate * 8 + 0 + b]);
                        pp[gate * 8 + 4 + b] = fmaf(hs, wq.y, pp[gate * 8 + 4 + b]);
                    }
                }
            }

        // ---- butterfly: lane ends with total for idx = bitrev5(lane&31) ----
        rstep<1, 16>(pp, lane);
        rstep<2, 8>(pp, lane);
        rstep<4, 4>(pp, lane);
        rstep<8, 2>(pp, lane);
        rstep<16, 1>(pp, lane);
        float v0 = pp[0] + __shfl_xor(pp[0], 32, 64);
        // act lane (gate bits = 0) gathers other gates from adjacent lanes:
        float zg = __shfl_xor(v0, 1, 64);   // gate 'g' (idx bit4 -> lane bit0)
        float zf = __shfl_xor(v0, 2, 64);   // gate 'f'
        float zo = __shfl_xor(v0, 3, 64);   // gate 'o'

        float hn = 0.f;
        if (act) {
            float z0 = xr[0] + v0;   // i
            float z1 = xr[1] + zf;   // f
            float z2 = xr[2] + zg;   // g
            float z3 = xr[3] + zo;   // o
            float si = 1.f / (1.f + expf(-z0));
            float sf = 1.f / (1.f + expf(-z1));
            float tg = tanhf(z2);
            float so = 1.f / (1.f + expf(-z3));
            float cn = sf * creg + si * tg;
            hn = so * tanhf(cn);
            creg = cn;
        }
        // drain: poison (and all older VMEM) at coherence point BEFORE h_{t+1}
        // becomes visible -- consumers seeing h_{t+1} may trust the recycle
        // buffer contains only poison-or-newer.
        asm volatile("s_waitcnt vmcnt(0)" ::: "memory");
        if (act) {
            __hip_atomic_store(hbuf + (size_t)nxt * HSZ + (size_t)B * 512 + col,
                               hn, __ATOMIC_RELAXED, __HIP_MEMORY_SCOPE_AGENT);
            // post-critical-path: out store + next xp prefetch
            out[((size_t)B * TT + t) * 512 + col] = hn;
            if (tl + 1 < T_CH) {
#pragma unroll
                for (int gate = 0; gate < 4; ++gate)
                    xn[gate] = xp[(((size_t)(tl + 1) * 4 + gate) * 32 + B) * 512 + col];
            }
#pragma unroll
            for (int gate = 0; gate < 4; ++gate) xr[gate] = xn[gate];
        }
    }

    // persist c for next chunk launch (plain; kernel-boundary coherence)
    if (act) cbuf[(size_t)B * 512 + col] = creg;
}

// ---------------------------------------------------------------------------
extern "C" void kernel_launch(void* const* d_in, const int* in_sizes, int n_in,
                              void* d_out, int out_size, void* d_ws, size_t ws_size,
                              hipStream_t stream) {
    const float* inputs = (const float*)d_in[0];
    // d_in[1] = input_paddings: unused (reference discards it)
    const float* c0   = (const float*)d_in[2];
    const float* h0   = (const float*)d_in[3];
    const float* Wi   = (const float*)d_in[4];
    const float* Wh   = (const float*)d_in[5];
    const float* bias = (const float*)d_in[6];
    float* out = (float*)d_out;

    // ws layout (floats): [hbuf 3*16384][cbuf 16384][xp]
    float* ws_f = (float*)d_ws;
    float* hbuf = ws_f;                              // 49152 floats
    float* cbuf = ws_f + 3 * HSZ;                    // 16384 floats
    float* xp   = ws_f + 3 * HSZ + HSZ;              // offset 65536 (16B aligned)
    const size_t extras_bytes = (size_t)(4 * HSZ) * sizeof(float);

    // pick largest T-chunk (pow2, <=256) whose xp slab fits in ws
    int T_CH = 256;
    while (T_CH > 32 &&
           extras_bytes + (size_t)T_CH * 65536 * sizeof(float) > ws_size)
        T_CH >>= 1;
    int tlog = 31 - __builtin_clz((unsigned)T_CH);

    // poison all 3 h buffers (0xFF bytes -> 0xFFFFFFFF words) before t0=0;
    // the scan kernel fills buf[0] with h0 in-kernel (polling is the sync).
    hipMemsetAsync(hbuf, 0xFF, (size_t)(3 * HSZ) * sizeof(float), stream);

    for (int t0 = 0; t0 < TT; t0 += T_CH) {
        dim3 g1(2048 / BN, (32 * T_CH) / BM);
        xproj_gemm<<<g1, 256, 0, stream>>>(inputs, Wi, bias, xp, t0, T_CH - 1, tlog);

        const float* xp_c = xp;
        int t0_arg = t0, tch_arg = T_CH;
        void* args[] = { (void*)&xp_c, (void*)&Wh, (void*)&c0, (void*)&h0,
                         (void*)&out, (void*)&hbuf, (void*)&cbuf,
                         (void*)&t0_arg, (void*)&tch_arg };
        hipLaunchCooperativeKernel((const void*)lstm_scan, dim3(NGRP * BPG), dim3(512),
                                   args, 0, stream);
    }
}

// Round 6
// 7846.717 us; speedup vs baseline: 2.0720x; 2.0720x over previous
//
#include <hip/hip_runtime.h>
#include <cstdint>
#include <cstddef>

// Problem dims: B=32, T=2048, D=512, H=512, 4H=2048
#define TT 2048
#define DD 512

// ---------------------------------------------------------------------------
// Phase 1 (chunked): xp = inputs @ Wi + b, layout: xp[tl][gate 4][B 32][col 512]
// fp32 vector GEMM, 128x128x16 tiles, 8x8 per thread.  (unchanged)
// ---------------------------------------------------------------------------
#define BM 128
#define BN 128
#define BK 16

__global__ __launch_bounds__(256) void xproj_gemm(
    const float* __restrict__ A,    // [32*2048, 512]
    const float* __restrict__ W,    // [512, 2048]
    const float* __restrict__ bias, // [2048]
    float* __restrict__ C,          // xp chunk
    int t0, int tmask, int tlog)    // T_CH = tmask+1 = 1<<tlog
{
    __shared__ __align__(16) float As[BK][BM + 4];   // [k][m], transposed on load
    __shared__ __align__(16) float Bs[BK][BN + 4];   // [k][n]
    const int tid = threadIdx.x;
    const int nt = blockIdx.x;
    const int mt = blockIdx.y;
    const int m_base = mt * BM;        // chunk-local row (m = bglob*T_CH + tl)
    const int n_base = nt * BN;
    const int ty = tid >> 4;
    const int tx = tid & 15;

    float acc[8][8];
#pragma unroll
    for (int i = 0; i < 8; ++i)
#pragma unroll
        for (int j = 0; j < 8; ++j) acc[i][j] = 0.f;

    for (int k0 = 0; k0 < DD; k0 += BK) {
#pragma unroll
        for (int j = 0; j < 2; ++j) {
            int idx = tid * 2 + j;             // 0..511
            int rowl = idx >> 2, q = idx & 3;  // A: 128 rows x 4 float4
            int rc = m_base + rowl;            // chunk-local row
            int rg = ((rc >> tlog) << 11) + t0 + (rc & tmask);  // global input row
            float4 av = *(const float4*)(A + (size_t)rg * DD + k0 + q * 4);
            As[q * 4 + 0][rowl] = av.x;
            As[q * 4 + 1][rowl] = av.y;
            As[q * 4 + 2][rowl] = av.z;
            As[q * 4 + 3][rowl] = av.w;
            int kr = idx >> 5, nq = idx & 31;  // B: 16 rows x 32 float4
            *(float4*)&Bs[kr][nq * 4] =
                *(const float4*)(W + (size_t)(k0 + kr) * 2048 + n_base + nq * 4);
        }
        __syncthreads();
#pragma unroll
        for (int kk = 0; kk < BK; ++kk) {
            float a[8], bb[8];
            *(float4*)&a[0]  = *(const float4*)&As[kk][ty * 8];
            *(float4*)&a[4]  = *(const float4*)&As[kk][ty * 8 + 4];
            *(float4*)&bb[0] = *(const float4*)&Bs[kk][tx * 8];
            *(float4*)&bb[4] = *(const float4*)&Bs[kk][tx * 8 + 4];
#pragma unroll
            for (int i = 0; i < 8; ++i)
#pragma unroll
                for (int j = 0; j < 8; ++j)
                    acc[i][j] = fmaf(a[i], bb[j], acc[i][j]);
        }
        __syncthreads();
    }
#pragma unroll
    for (int i = 0; i < 8; ++i) {
        int m = m_base + ty * 8 + i;
        int bglob = m >> tlog, tl = m & tmask;
#pragma unroll
        for (int j = 0; j < 8; j += 4) {
            int n = n_base + tx * 8 + j;
            int gate = n >> 9, c = n & 511;    // 8-aligned run never crosses gate
            float4 v;
            v.x = acc[i][j + 0] + bias[n + 0];
            v.y = acc[i][j + 1] + bias[n + 1];
            v.z = acc[i][j + 2] + bias[n + 2];
            v.w = acc[i][j + 3] + bias[n + 3];
            size_t addr = (((size_t)tl * 4 + gate) * 32 + bglob) * 512 + c;
            *(float4*)(C + addr) = v;
        }
    }
}

// ---------------------------------------------------------------------------
// Phase 2: persistent LSTM scan.
// Data plan (R2's proven winner): Wh slice in LDS, re-read per step (cheap,
// 128 B/thread/step); h staged once per CU into double-buffered LDS.
// Sync plan: data-poll (R4's poison protocol, no flags/barriers between
// blocks) + ONE __syncthreads per step. Gates within-wave (R3/R5 mapping).
//
// Geometry: 8 groups x 32 blocks x 512 threads (1 block/CU). Group g owns
// batches [4g,4g+4). Block p owns cols [16p,16p+16). Wave w owns cols
// {16p+2w, 16p+2w+1}, all 4 gates, all 4 batches. Lane l owns
// k in {4l..4l+3} U {256+4l..256+4l+3}.
//
// Poison protocol: h rotates through 3 buffers; slot owner poisons its
// recycle slot AFTER the block-wide poll + syncthreads (proves every group
// block consumed h_{t-1}); vmcnt(0) drain orders poison before the h-store
// (drain-then-signal, data = signal). 0xFFFFFFFF is NaN, unreachable by
// h = o*tanh(c) in (-1,1).
// ---------------------------------------------------------------------------
#define NGRP 8
#define BPG  32
#define HSZ  (32 * 512)          // one h buffer (floats)
#define POISON 0xFFFFFFFFu
#define WHST 516                 // padded wh row stride (floats, mult of 4)

__device__ __forceinline__ float ldg_agent_f32(const float* p) {
    return __hip_atomic_load(p, __ATOMIC_RELAXED, __HIP_MEMORY_SCOPE_AGENT);
}

// butterfly reduce step: halve the live value count across lanes differing in bit D
template<int D, int HALF>
__device__ __forceinline__ void rstep(float* p, int lane) {
    const bool hi = (lane & D) != 0;
#pragma unroll
    for (int i = 0; i < HALF; ++i) {
        float send = hi ? p[i] : p[i + HALF];
        float recv = __shfl_xor(send, D, 64);
        p[i] = (hi ? p[i + HALF] : p[i]) + recv;
    }
}

__global__ __launch_bounds__(512) void lstm_scan(
    const float* __restrict__ xp,   // [tl][gate 4][B 32][col 512]
    const float* __restrict__ Wh,   // [512, 2048]
    const float* __restrict__ c0,   // [32, 512]
    const float* __restrict__ h0,   // [32, 512]
    float* __restrict__ out,        // [32, 2048, 512]
    float* hbuf,                    // [3][32][512] rotating (persists)
    float* __restrict__ cbuf,       // [32][512] c-state (persists)
    int t0, int T_CH)
{
    __shared__ float wh[64 * WHST];   // [gate*16 + local_col][k]  132,096 B
    __shared__ float hs[2 * 4 * 512]; // double-buffered [buf][b][k] 16,384 B

    const int tid  = threadIdx.x;
    const int blk  = blockIdx.x;
    const int g    = blk >> 5;      // group 0..7 (4 batches each)
    const int p    = blk & 31;      // block-in-group (16 cols each)
    const int j0   = p * 16;
    const int lane = tid & 63;
    const int w    = tid >> 6;      // wave 0..7

    // lane<32 role decode: idx = bitrev5(lane) = gate*8 + cc*4 + b
    const int idx = ((lane & 1) << 4) | ((lane & 2) << 2) | (lane & 4)
                  | ((lane >> 2) & 2) | ((lane >> 4) & 1);
    const int gate = idx >> 3;
    const int cc   = (idx >> 2) & 1;
    const int bq   = idx & 3;
    const int B    = 4 * g + bq;
    const int col  = j0 + 2 * w + cc;
    const bool low = lane < 32;
    const bool act = low && ((lane & 3) == 0);   // idx<8 -> gate==0 owner lanes

    // ---- h0 / creg init (issue h0 stores FIRST so peers' polls clear) ----
    float creg = 0.f;
    if (act) {
        size_t o = (size_t)B * 512 + col;
        if (t0 == 0) {
            creg = c0[o];
            float hv = h0[o];
            if (__float_as_uint(hv) == POISON) hv = __uint_as_float(0xFFFFFFFEu);
            __hip_atomic_store(hbuf + o, hv, __ATOMIC_RELAXED, __HIP_MEMORY_SCOPE_AGENT);
        } else {
            creg = cbuf[o];   // h_{t0} already in hbuf[t0%3] from prev chunk
        }
    }

    // ---- stage Wh slice into LDS (once per launch) ----
    // wh[(gt*16 + lc)][k] = Wh[k][gt*512 + j0 + lc], lc = 0..15
#pragma unroll
    for (int i = 0; i < 16; ++i) {
        int id = tid + i * 512;            // 0..8191
        int q4 = id & 3, gt = (id >> 2) & 3, k = id >> 4;
        float4 v = *(const float4*)(Wh + (size_t)k * 2048 + gt * 512 + j0 + q4 * 4);
        int r0 = gt * 16 + q4 * 4;
        wh[(r0 + 0) * WHST + k] = v.x;
        wh[(r0 + 1) * WHST + k] = v.y;
        wh[(r0 + 2) * WHST + k] = v.z;
        wh[(r0 + 3) * WHST + k] = v.w;
    }

    // staging role: batch sb = w>>1, half sh = (w&1)*256, 4 slots (q*64+lane)
    const int sb = w >> 1;
    const int sh = (w & 1) * 256;

    // xp prefetch for tl=0 (one float per low lane: its (gate,B,col))
    float xr = 0.f, xn = 0.f;
    if (low) xr = xp[((size_t)gate * 32 + B) * 512 + col];

    __syncthreads();   // wh ready

    for (int tl = 0; tl < T_CH; ++tl) {
        const int t = t0 + tl;
        const int cur = t % 3;             // read h_t
        const int nxt = (t + 1) % 3;       // write h_{t+1}
        const int rcy = (t + 2) % 3;       // poison own slot (holds dead h_{t-1})

        // issue next-step xp prefetch (in flight across poll+dot)
        if (low && (tl + 1 < T_CH))
            xn = xp[((size_t)((tl + 1) * 4 + gate) * 32 + B) * 512 + col];

        // ---- poll own 4 slots of h_t (data IS the signal) ----
        const float* hsrc = hbuf + (size_t)cur * HSZ
                          + (size_t)(4 * g + sb) * 512 + sh + lane;
        float hvv[4];
        for (;;) {
            bool ok = true;
#pragma unroll
            for (int q = 0; q < 4; ++q) {
                hvv[q] = ldg_agent_f32(hsrc + q * 64);
                ok = ok & (__float_as_uint(hvv[q]) != POISON);
            }
            if (ok) break;
            __builtin_amdgcn_s_sleep(1);
        }
        float* hdst = hs + (tl & 1) * 2048 + sb * 512 + sh + lane;
#pragma unroll
        for (int q = 0; q < 4; ++q) hdst[q * 64] = hvv[q];
        __syncthreads();   // block-wide: h_t staged AND fully consumed

        // ---- poison recycle slot (safe: all group blocks consumed h_{t-1},
        // since h_t complete implies every group block finished step t-1) ----
        if (act)
            __hip_atomic_store(hbuf + (size_t)rcy * HSZ + (size_t)B * 512 + col,
                               __uint_as_float(POISON),
                               __ATOMIC_RELAXED, __HIP_MEMORY_SCOPE_AGENT);

        // ---- dot: pp[gate*8 + cc*4 + b] over this lane's 8 k ----
        const float* hb = hs + (tl & 1) * 2048;
        float4 ha[4], h2[4];
#pragma unroll
        for (int b = 0; b < 4; ++b) {
            ha[b] = *(const float4*)(hb + b * 512 + 4 * lane);
            h2[b] = *(const float4*)(hb + b * 512 + 256 + 4 * lane);
        }
        float pp[32];
#pragma unroll
        for (int i = 0; i < 32; ++i) pp[i] = 0.f;
#pragma unroll
        for (int gt = 0; gt < 4; ++gt)
#pragma unroll
            for (int c2 = 0; c2 < 2; ++c2) {
                const float* wr = wh + (size_t)(gt * 16 + 2 * w + c2) * WHST + 4 * lane;
                float4 w0 = *(const float4*)wr;
                float4 w1 = *(const float4*)(wr + 256);
#pragma unroll
                for (int b = 0; b < 4; ++b) {
                    float a = pp[gt * 8 + c2 * 4 + b];
                    a = fmaf(ha[b].x, w0.x, a);
                    a = fmaf(ha[b].y, w0.y, a);
                    a = fmaf(ha[b].z, w0.z, a);
                    a = fmaf(ha[b].w, w0.w, a);
                    a = fmaf(h2[b].x, w1.x, a);
                    a = fmaf(h2[b].y, w1.y, a);
                    a = fmaf(h2[b].z, w1.z, a);
                    a = fmaf(h2[b].w, w1.w, a);
                    pp[gt * 8 + c2 * 4 + b] = a;
                }
            }

        // ---- butterfly: lane ends with total for idx = bitrev5(lane&31) ----
        rstep<1, 16>(pp, lane);
        rstep<2, 8>(pp, lane);
        rstep<4, 4>(pp, lane);
        rstep<8, 2>(pp, lane);
        rstep<16, 1>(pp, lane);
        float v0 = pp[0] + __shfl_xor(pp[0], 32, 64);

        // ---- distributed activation: each low lane applies its gate's fn ----
        float av = 0.f;
        if (low) {
            float zz = v0 + xr;
            av = (gate == 2) ? tanhf(zz) : 1.f / (1.f + expf(-zz));
        }
        // gathers (R3/R5-verified): +16 -> xor1 (g), +8 -> xor2 (f), +24 -> xor3 (o)
        float ag = __shfl_xor(av, 1, 64);
        float af = __shfl_xor(av, 2, 64);
        float ao = __shfl_xor(av, 3, 64);

        float hn = 0.f;
        if (act) {
            float cn = af * creg + av * ag;   // sf*c + si*tg
            hn = ao * tanhf(cn);
            creg = cn;
        }
        // drain: poison (issued pre-dot, long acked) + everything older at the
        // coherence point BEFORE h_{t+1} becomes visible.
        asm volatile("s_waitcnt vmcnt(0)" ::: "memory");
        if (act) {
            __hip_atomic_store(hbuf + (size_t)nxt * HSZ + (size_t)B * 512 + col,
                               hn, __ATOMIC_RELAXED, __HIP_MEMORY_SCOPE_AGENT);
            out[((size_t)B * TT + t) * 512 + col] = hn;   // post-critical-path
        }
        if (low) xr = xn;
    }

    // persist c for next chunk launch (plain; kernel-boundary coherence)
    if (act) cbuf[(size_t)B * 512 + col] = creg;
}

// ---------------------------------------------------------------------------
extern "C" void kernel_launch(void* const* d_in, const int* in_sizes, int n_in,
                              void* d_out, int out_size, void* d_ws, size_t ws_size,
                              hipStream_t stream) {
    const float* inputs = (const float*)d_in[0];
    // d_in[1] = input_paddings: unused (reference discards it)
    const float* c0   = (const float*)d_in[2];
    const float* h0   = (const float*)d_in[3];
    const float* Wi   = (const float*)d_in[4];
    const float* Wh   = (const float*)d_in[5];
    const float* bias = (const float*)d_in[6];
    float* out = (float*)d_out;

    // ws layout (floats): [hbuf 3*16384][cbuf 16384][xp]
    float* ws_f = (float*)d_ws;
    float* hbuf = ws_f;                              // 49152 floats
    float* cbuf = ws_f + 3 * HSZ;                    // 16384 floats
    float* xp   = ws_f + 4 * HSZ;                    // offset 65536 (16B aligned)
    const size_t extras_bytes = (size_t)(4 * HSZ) * sizeof(float);

    // pick largest T-chunk (pow2, <=256) whose xp slab fits in ws
    int T_CH = 256;
    while (T_CH > 32 &&
           extras_bytes + (size_t)T_CH * 65536 * sizeof(float) > ws_size)
        T_CH >>= 1;
    int tlog = 31 - __builtin_clz((unsigned)T_CH);

    // poison all 3 h buffers (0xFF bytes -> 0xFFFFFFFF words) before t0=0;
    // the scan kernel fills buf[0] with h0 in-kernel (polling is the sync).
    hipMemsetAsync(hbuf, 0xFF, (size_t)(3 * HSZ) * sizeof(float), stream);

    for (int t0 = 0; t0 < TT; t0 += T_CH) {
        dim3 g1(2048 / BN, (32 * T_CH) / BM);
        xproj_gemm<<<g1, 256, 0, stream>>>(inputs, Wi, bias, xp, t0, T_CH - 1, tlog);

        const float* xp_c = xp;
        int t0_arg = t0, tch_arg = T_CH;
        void* args[] = { (void*)&xp_c, (void*)&Wh, (void*)&c0, (void*)&h0,
                         (void*)&out, (void*)&hbuf, (void*)&cbuf,
                         (void*)&t0_arg, (void*)&tch_arg };
        hipLaunchCooperativeKernel((const void*)lstm_scan, dim3(NGRP * BPG), dim3(512),
                                   args, 0, stream);
    }
}